// Round 6
// baseline (571.780 us; speedup 1.0000x reference)
//
#include <hip/hip_runtime.h>

typedef __attribute__((ext_vector_type(4))) float floatx4;
typedef __attribute__((ext_vector_type(8))) int   intx8;

// ---------------------------------------------------------------------------
// pack 4 floats (already clipped to +-448) into 4 e4m3 bytes, RNE
// ---------------------------------------------------------------------------
__device__ __forceinline__ unsigned int pack4_fp8(float f0, float f1, float f2, float f3) {
    int v = __builtin_amdgcn_cvt_pk_fp8_f32(f0, f1, 0, false);   // bytes 0,1
    v = __builtin_amdgcn_cvt_pk_fp8_f32(f2, f3, v, true);        // bytes 2,3
    return (unsigned int)v;
}

// async global->LDS, 16 B per lane. LDS dest is wave-uniform; HW writes
// dest + lane*16. Global src is per-lane (pre-swizzled to match).
__device__ __forceinline__ void gload16(const unsigned char* g, unsigned char* l) {
    __builtin_amdgcn_global_load_lds(
        (const __attribute__((address_space(1))) unsigned int*)g,
        (__attribute__((address_space(3))) unsigned int*)l, 16, 0, 0);
}

// ---------------------------------------------------------------------------
// Kernel 0: classify the weight buffer's on-device dtype.
// flag: 0 = raw fp8 bytes, 1 = bf16-upcast, 2 = f32-upcast.
// ---------------------------------------------------------------------------
__global__ void detect_kernel(const unsigned int* __restrict__ W, int* __restrict__ flag) {
    __shared__ int ok[2];  // [f32ok, bf16ok]
    if (threadIdx.x == 0) { ok[0] = 1; ok[1] = 1; }
    __syncthreads();
    int f32ok = 1, bf16ok = 1;
#pragma unroll
    for (int i = 0; i < 16; ++i) {
        unsigned int w = W[threadIdx.x * 16 + i];   // first 16 KB of buffer
        if (w & 0x000FFFFFu) f32ok = 0;
        if (w & 0x000F000Fu) bf16ok = 0;
    }
    if (!f32ok)  atomicAnd(&ok[0], 0);
    if (!bf16ok) atomicAnd(&ok[1], 0);
    __syncthreads();
    if (threadIdx.x == 0) *flag = ok[0] ? 2 : (ok[1] ? 1 : 0);
}

// ---------------------------------------------------------------------------
// Kernel 1: quantize x (fp32) -> q (fp8 e4m3fn), q = clip(x/s, +-448)
// ---------------------------------------------------------------------------
__global__ void quant_kernel(const float* __restrict__ x,
                             unsigned int* __restrict__ q,
                             const float* __restrict__ iscale, int n8) {
    int i = blockIdx.x * blockDim.x + threadIdx.x;
    if (i >= n8) return;
    float s = iscale[0];
    const float4* xv = (const float4*)x;
    float4 a = xv[2 * i];
    float4 b = xv[2 * i + 1];
    float v[8] = {a.x, a.y, a.z, a.w, b.x, b.y, b.z, b.w};
#pragma unroll
    for (int j = 0; j < 8; ++j) {
        float t = v[j] / s;
        v[j] = fminf(fmaxf(t, -448.0f), 448.0f);
    }
    q[2 * i]     = pack4_fp8(v[0], v[1], v[2], v[3]);
    q[2 * i + 1] = pack4_fp8(v[4], v[5], v[6], v[7]);
}

// ---------------------------------------------------------------------------
// Kernel 2: ingest weight [K,N] (any of the 3 dtypes) -> Wt [N,K] fp8 bytes,
// via 64x64 LDS tile. Single launch; runtime uniform branch on *flag.
// ---------------------------------------------------------------------------
template <int MODE>
__device__ __forceinline__ void ingest_body(const unsigned char* __restrict__ W,
                                            unsigned char* __restrict__ Wt,
                                            int K, int N,
                                            unsigned char (*tile)[68]) {
    const int k0 = blockIdx.y * 64;
    const int n0 = blockIdx.x * 64;
    const int t = threadIdx.x;          // 256 threads
    const int kr = t >> 2;              // k-row within tile
    const int cg = (t & 3) * 16;        // n-column group (16 values)
    const size_t eidx = (size_t)(k0 + kr) * N + (n0 + cg);  // element index

    unsigned int w4[4];
    if constexpr (MODE == 0) {          // raw fp8 bytes
        uint4 v = *(const uint4*)(W + eidx);
        w4[0] = v.x; w4[1] = v.y; w4[2] = v.z; w4[3] = v.w;
    } else if constexpr (MODE == 1) {   // bf16-upcast (2 B/elem)
        const uint4* p = (const uint4*)((const unsigned short*)W + eidx);
        uint4 A0 = p[0], A1 = p[1];
        unsigned int uw[8] = {A0.x, A0.y, A0.z, A0.w, A1.x, A1.y, A1.z, A1.w};
#pragma unroll
        for (int g = 0; g < 4; ++g) {
            float f0 = __uint_as_float((uw[2 * g] & 0xFFFFu) << 16);
            float f1 = __uint_as_float((uw[2 * g] >> 16) << 16);
            float f2 = __uint_as_float((uw[2 * g + 1] & 0xFFFFu) << 16);
            float f3 = __uint_as_float((uw[2 * g + 1] >> 16) << 16);
            w4[g] = pack4_fp8(f0, f1, f2, f3);
        }
    } else {                            // f32-upcast (4 B/elem)
        const float4* p = (const float4*)((const float*)W + eidx);
#pragma unroll
        for (int g = 0; g < 4; ++g) {
            float4 f = p[g];
            w4[g] = pack4_fp8(f.x, f.y, f.z, f.w);
        }
    }
#pragma unroll
    for (int g = 0; g < 4; ++g)
        *(unsigned int*)&tile[kr][cg + 4 * g] = w4[g];   // 4B-aligned (68%4==0)
    __syncthreads();

    const int nr = t >> 2;
    const int kg = (t & 3) * 16;
    uint4 o;
    unsigned int w[4];
#pragma unroll
    for (int g = 0; g < 4; ++g) {
        unsigned int b0 = tile[kg + g * 4 + 0][nr];
        unsigned int b1 = tile[kg + g * 4 + 1][nr];
        unsigned int b2 = tile[kg + g * 4 + 2][nr];
        unsigned int b3 = tile[kg + g * 4 + 3][nr];
        w[g] = b0 | (b1 << 8) | (b2 << 16) | (b3 << 24);
    }
    o.x = w[0]; o.y = w[1]; o.z = w[2]; o.w = w[3];
    *(uint4*)(Wt + (size_t)(n0 + nr) * K + k0 + kg) = o;  // 16B-aligned
}

__global__ void ingest_kernel(const unsigned char* __restrict__ W,
                              unsigned char* __restrict__ Wt,
                              const int* __restrict__ flag, int K, int N) {
    __shared__ __align__(16) unsigned char tile[64][68];
    const int mode = *flag;             // global & uniform -> no divergence
    if (mode == 0)      ingest_body<0>(W, Wt, K, N, tile);
    else if (mode == 1) ingest_body<1>(W, Wt, K, N, tile);
    else                ingest_body<2>(W, Wt, K, N, tile);
}

// ---------------------------------------------------------------------------
// Kernel 3: MX-scaled fp8 GEMM (scales = 1.0), 256x256 tile, BK=128,
// 8 waves (2M x 4N), ONE barrier-pair per K-tile.
//
// ROUND-6 THEORY TEST: rounds 1-5 pin at 19-24.5% MfmaUtil across occupancy
// 22<->42%, mono<->4-phase, drain0<->counted. Re-fit: each phase's barrier
// PAIR converts per-wave jitter (LDS-port stagger ~770cy, MFMA pipe
// serialization ~550cy across 2 waves/SIMD) into a block-wide max:
// H ~ 1600 cy/phase, 4 phases -> the measured 8660 cy/tile vs 2200 pipe.
// This round holds EVERYTHING fixed except phase count: 1 barrier-pair/tile.
//   tile u: DMA A(u+1),B(u+1) -> [(u+1)&1] bufs (their previous readers
//           finished before boundary(u-1): lgkm(0) precedes their MFMA
//           precedes that barrier -> WAR-safe);
//           24 ds_reads (two reg batches, per-wave lgkm waits, NO barrier
//           between batches); s_barrier; lgkm(0); 16 MFMA; batch-2 lgkm(0);
//           16 MFMA; vmcnt(0); s_barrier.
// vmcnt(0) at the boundary is free-by-construction: loads span the whole
// tile body (~3000+ cy >> 900 cy HBM latency) -- T4's real content.
// setprio dropped (single cluster, lockstep = m190's null regime).
//
// LDS layout & 16x16x128 f8f6f4 fragment mapping: verified rounds 1-5
// (0 bank conflicts, correctness passed).
// ---------------------------------------------------------------------------
__global__ __launch_bounds__(512, 2) void gemm_mxfp8_kernel(
    const unsigned char* __restrict__ A,   // [M,K] fp8
    const unsigned char* __restrict__ Bt,  // [N,K] fp8
    float* __restrict__ C,                 // [M,N] fp32
    const float* __restrict__ bias,        // [N]
    const float* __restrict__ wscale,
    const float* __restrict__ iscale,
    int M, int N, int K) {
    __shared__ __align__(16) unsigned char As[2 * 32768];
    __shared__ __align__(16) unsigned char Bs[2 * 32768];

    const int tid  = threadIdx.x;
    const int lane = tid & 63;
    const int wv   = tid >> 6;          // 8 waves
    const int wm   = wv >> 2;           // 2 (M) x 4 (N) wave grid
    const int wn   = wv & 3;
    const int r16  = lane & 15;
    const int cq   = lane >> 4;         // 0..3

    const int bm = blockIdx.y * 256;    // linear block order (round-2 measured)
    const int bn = blockIdx.x * 256;

    // staging: 32 x 1 KB units per operand tile; wave wv owns units wv*4+j
    const unsigned char* ga[4];
    const unsigned char* gb[4];
    int lo[4];
#pragma unroll
    for (int j = 0; j < 4; ++j) {
        const int u   = wv * 4 + j;     // 0..31
        const int rb  = u >> 1;
        const int rg  = u & 1;
        const int row = rb * 16 + r16;
        const int col = cq * 32 + rg * 16;   // per-lane pre-swizzled source
        ga[j] = A  + (size_t)(bm + row) * K + col;
        gb[j] = Bt + (size_t)(bn + row) * K + col;
        lo[j] = u * 1024;                    // wave-uniform LDS offset
    }

    floatx4 acc[8][4] = {};
    const int NT = K >> 7;              // K / 128

    // prologue: stage tile 0 into buffer 0, full drain once
#pragma unroll
    for (int j = 0; j < 4; ++j) {
        gload16(ga[j], &As[lo[j]]);
        gload16(gb[j], &Bs[lo[j]]);
        ga[j] += 128; gb[j] += 128;
    }
    asm volatile("s_waitcnt vmcnt(0)" ::: "memory");
    __builtin_amdgcn_s_barrier();
    __builtin_amdgcn_sched_barrier(0);

    union U8 { intx8 v; uint4 q[2]; };

#define READ_FRAG(dst, base, blk)                                   \
    do {                                                            \
        U8 _u;                                                      \
        const unsigned char* _p = (base) + (blk) * 2048 + lane * 16;\
        _u.q[0] = *(const uint4*)_p;                                \
        _u.q[1] = *(const uint4*)(_p + 1024);                       \
        (dst) = _u.v;                                               \
    } while (0)

#define MFMA16(af_, ibase)                                                  \
    do {                                                                    \
        _Pragma("unroll")                                                   \
        for (int i = 0; i < 4; ++i)                                         \
            _Pragma("unroll")                                               \
            for (int j = 0; j < 4; ++j)                                     \
                acc[(ibase) + i][j] =                                       \
                    __builtin_amdgcn_mfma_scale_f32_16x16x128_f8f6f4(       \
                        af_[i], bf[j], acc[(ibase) + i][j],                 \
                        0, 0, 0, 0x7F7F7F7F, 0, 0x7F7F7F7F);                \
    } while (0)

    for (int kt = 0; kt < NT; ++kt) {
        const unsigned char* Ab = &As[(kt & 1) * 32768];
        const unsigned char* Bb = &Bs[(kt & 1) * 32768];
        unsigned char* An = &As[((kt + 1) & 1) * 32768];
        unsigned char* Bn = &Bs[((kt + 1) & 1) * 32768];

        // DMA next tile (1-ahead, other buffers). WAR-safe: previous readers
        // of those buffers finished before the PREVIOUS boundary barrier.
        if (kt + 1 < NT) {
#pragma unroll
            for (int j = 0; j < 4; ++j) {
                gload16(ga[j], An + lo[j]);
                gload16(gb[j], Bn + lo[j]);
                ga[j] += 128; gb[j] += 128;
            }
        }

        // batch 1: all B frags + A blocks 0-3 (16 ds_read_b128)
        intx8 bf[4], af1[4], af2[4];
        READ_FRAG(bf[0], Bb, wn * 4 + 0);
        READ_FRAG(bf[1], Bb, wn * 4 + 1);
        READ_FRAG(bf[2], Bb, wn * 4 + 2);
        READ_FRAG(bf[3], Bb, wn * 4 + 3);
        READ_FRAG(af1[0], Ab, wm * 8 + 0);
        READ_FRAG(af1[1], Ab, wm * 8 + 1);
        READ_FRAG(af1[2], Ab, wm * 8 + 2);
        READ_FRAG(af1[3], Ab, wm * 8 + 3);

        __builtin_amdgcn_s_barrier();                      // ONE barrier
        asm volatile("s_waitcnt lgkmcnt(0)" ::: "memory"); // batch-1 landed
        __builtin_amdgcn_sched_barrier(0);

        // batch 2 issue (8 reads) overlaps MFMA group 1's pipe time
        READ_FRAG(af2[0], Ab, wm * 8 + 4);
        READ_FRAG(af2[1], Ab, wm * 8 + 5);
        READ_FRAG(af2[2], Ab, wm * 8 + 6);
        READ_FRAG(af2[3], Ab, wm * 8 + 7);

        MFMA16(af1, 0);

        asm volatile("s_waitcnt lgkmcnt(0)" ::: "memory"); // batch-2 landed
        __builtin_amdgcn_sched_barrier(0);

        MFMA16(af2, 4);

        // boundary: loads spanned the whole tile -> drain is ~free
        asm volatile("s_waitcnt vmcnt(0)" ::: "memory");
        __builtin_amdgcn_s_barrier();
        __builtin_amdgcn_sched_barrier(0);
    }
    (void)M;
#undef READ_FRAG
#undef MFMA16

    const float scale = iscale[0] * wscale[0];
    const int row0 = bm + wm * 128 + (cq << 2);  // C/D: col=lane&15, row=cq*4+r
    const int col0 = bn + wn * 64 + r16;
#pragma unroll
    for (int j = 0; j < 4; ++j) {
        const int col = col0 + j * 16;
        const float bv = bias[col];
#pragma unroll
        for (int i = 0; i < 8; ++i) {
            const int row = row0 + i * 16;
            float* cp = C + (size_t)row * N + col;
#pragma unroll
            for (int r = 0; r < 4; ++r)
                cp[(size_t)r * N] = acc[i][j][r] * scale + bv;
        }
    }
}

extern "C" void kernel_launch(void* const* d_in, const int* in_sizes, int n_in,
                              void* d_out, int out_size, void* d_ws, size_t ws_size,
                              hipStream_t stream) {
    const float* x          = (const float*)d_in[0];
    const unsigned char* w  = (const unsigned char*)d_in[1];
    const float* wscale     = (const float*)d_in[2];
    const float* iscale     = (const float*)d_in[3];
    const float* bias       = (const float*)d_in[4];
    float* out              = (float*)d_out;

    const int D_OUT = in_sizes[4];            // 8192
    const int D_IN  = in_sizes[1] / D_OUT;    // 2048
    const int M     = in_sizes[0] / D_IN;     // 8192

    int* flag         = (int*)d_ws;
    unsigned char* q  = (unsigned char*)d_ws + 256;
    unsigned char* wt = q + (size_t)M * D_IN;

    detect_kernel<<<1, 256, 0, stream>>>((const unsigned int*)w, flag);
    const int n8 = (M * D_IN) / 8;
    quant_kernel<<<(n8 + 255) / 256, 256, 0, stream>>>(x, (unsigned int*)q, iscale, n8);
    dim3 tg(D_OUT / 64, D_IN / 64);
    ingest_kernel<<<tg, 256, 0, stream>>>(w, wt, flag, D_IN, D_OUT);
    gemm_mxfp8_kernel<<<dim3(D_OUT / 256, M / 256), 512, 0, stream>>>(
        q, wt, out, bias, wscale, iscale, M, D_OUT, D_IN);
}

// Round 7
// 507.411 us; speedup vs baseline: 1.1269x; 1.1269x over previous
//
#include <hip/hip_runtime.h>

typedef __attribute__((ext_vector_type(4)))  float floatx4;
typedef __attribute__((ext_vector_type(16))) float floatx16;
typedef __attribute__((ext_vector_type(8)))  int   intx8;

// ---------------------------------------------------------------------------
// pack 4 floats (already clipped to +-448) into 4 e4m3 bytes, RNE
// ---------------------------------------------------------------------------
__device__ __forceinline__ unsigned int pack4_fp8(float f0, float f1, float f2, float f3) {
    int v = __builtin_amdgcn_cvt_pk_fp8_f32(f0, f1, 0, false);   // bytes 0,1
    v = __builtin_amdgcn_cvt_pk_fp8_f32(f2, f3, v, true);        // bytes 2,3
    return (unsigned int)v;
}

// async global->LDS, 16 B per lane. LDS dest is wave-uniform; HW writes
// dest + lane*16. Global src is per-lane (pre-swizzled to match).
__device__ __forceinline__ void gload16(const unsigned char* g, unsigned char* l) {
    __builtin_amdgcn_global_load_lds(
        (const __attribute__((address_space(1))) unsigned int*)g,
        (__attribute__((address_space(3))) unsigned int*)l, 16, 0, 0);
}

// ---------------------------------------------------------------------------
// Kernel 0: classify the weight buffer's on-device dtype.
// flag: 0 = raw fp8 bytes, 1 = bf16-upcast, 2 = f32-upcast.
// ---------------------------------------------------------------------------
__global__ void detect_kernel(const unsigned int* __restrict__ W, int* __restrict__ flag) {
    __shared__ int ok[2];  // [f32ok, bf16ok]
    if (threadIdx.x == 0) { ok[0] = 1; ok[1] = 1; }
    __syncthreads();
    int f32ok = 1, bf16ok = 1;
#pragma unroll
    for (int i = 0; i < 16; ++i) {
        unsigned int w = W[threadIdx.x * 16 + i];   // first 16 KB of buffer
        if (w & 0x000FFFFFu) f32ok = 0;
        if (w & 0x000F000Fu) bf16ok = 0;
    }
    if (!f32ok)  atomicAnd(&ok[0], 0);
    if (!bf16ok) atomicAnd(&ok[1], 0);
    __syncthreads();
    if (threadIdx.x == 0) *flag = ok[0] ? 2 : (ok[1] ? 1 : 0);
}

// ---------------------------------------------------------------------------
// Kernel 1: quantize x (fp32) -> q (fp8 e4m3fn), q = clip(x/s, +-448)
// ---------------------------------------------------------------------------
__global__ void quant_kernel(const float* __restrict__ x,
                             unsigned int* __restrict__ q,
                             const float* __restrict__ iscale, int n8) {
    int i = blockIdx.x * blockDim.x + threadIdx.x;
    if (i >= n8) return;
    float s = iscale[0];
    const float4* xv = (const float4*)x;
    float4 a = xv[2 * i];
    float4 b = xv[2 * i + 1];
    float v[8] = {a.x, a.y, a.z, a.w, b.x, b.y, b.z, b.w};
#pragma unroll
    for (int j = 0; j < 8; ++j) {
        float t = v[j] / s;
        v[j] = fminf(fmaxf(t, -448.0f), 448.0f);
    }
    q[2 * i]     = pack4_fp8(v[0], v[1], v[2], v[3]);
    q[2 * i + 1] = pack4_fp8(v[4], v[5], v[6], v[7]);
}

// ---------------------------------------------------------------------------
// Kernel 2: ingest weight [K,N] (any of the 3 dtypes) -> Wt [N,K] fp8 bytes,
// via 64x64 LDS tile. Single launch; runtime uniform branch on *flag.
// ---------------------------------------------------------------------------
template <int MODE>
__device__ __forceinline__ void ingest_body(const unsigned char* __restrict__ W,
                                            unsigned char* __restrict__ Wt,
                                            int K, int N,
                                            unsigned char (*tile)[68]) {
    const int k0 = blockIdx.y * 64;
    const int n0 = blockIdx.x * 64;
    const int t = threadIdx.x;          // 256 threads
    const int kr = t >> 2;              // k-row within tile
    const int cg = (t & 3) * 16;        // n-column group (16 values)
    const size_t eidx = (size_t)(k0 + kr) * N + (n0 + cg);  // element index

    unsigned int w4[4];
    if constexpr (MODE == 0) {          // raw fp8 bytes
        uint4 v = *(const uint4*)(W + eidx);
        w4[0] = v.x; w4[1] = v.y; w4[2] = v.z; w4[3] = v.w;
    } else if constexpr (MODE == 1) {   // bf16-upcast (2 B/elem)
        const uint4* p = (const uint4*)((const unsigned short*)W + eidx);
        uint4 A0 = p[0], A1 = p[1];
        unsigned int uw[8] = {A0.x, A0.y, A0.z, A0.w, A1.x, A1.y, A1.z, A1.w};
#pragma unroll
        for (int g = 0; g < 4; ++g) {
            float f0 = __uint_as_float((uw[2 * g] & 0xFFFFu) << 16);
            float f1 = __uint_as_float((uw[2 * g] >> 16) << 16);
            float f2 = __uint_as_float((uw[2 * g + 1] & 0xFFFFu) << 16);
            float f3 = __uint_as_float((uw[2 * g + 1] >> 16) << 16);
            w4[g] = pack4_fp8(f0, f1, f2, f3);
        }
    } else {                            // f32-upcast (4 B/elem)
        const float4* p = (const float4*)((const float*)W + eidx);
#pragma unroll
        for (int g = 0; g < 4; ++g) {
            float4 f = p[g];
            w4[g] = pack4_fp8(f.x, f.y, f.z, f.w);
        }
    }
#pragma unroll
    for (int g = 0; g < 4; ++g)
        *(unsigned int*)&tile[kr][cg + 4 * g] = w4[g];   // 4B-aligned (68%4==0)
    __syncthreads();

    const int nr = t >> 2;
    const int kg = (t & 3) * 16;
    uint4 o;
    unsigned int w[4];
#pragma unroll
    for (int g = 0; g < 4; ++g) {
        unsigned int b0 = tile[kg + g * 4 + 0][nr];
        unsigned int b1 = tile[kg + g * 4 + 1][nr];
        unsigned int b2 = tile[kg + g * 4 + 2][nr];
        unsigned int b3 = tile[kg + g * 4 + 3][nr];
        w[g] = b0 | (b1 << 8) | (b2 << 16) | (b3 << 24);
    }
    o.x = w[0]; o.y = w[1]; o.z = w[2]; o.w = w[3];
    *(uint4*)(Wt + (size_t)(n0 + nr) * K + k0 + kg) = o;  // 16B-aligned
}

__global__ void ingest_kernel(const unsigned char* __restrict__ W,
                              unsigned char* __restrict__ Wt,
                              const int* __restrict__ flag, int K, int N) {
    __shared__ __align__(16) unsigned char tile[64][68];
    const int mode = *flag;             // global & uniform -> no divergence
    if (mode == 0)      ingest_body<0>(W, Wt, K, N, tile);
    else if (mode == 1) ingest_body<1>(W, Wt, K, N, tile);
    else                ingest_body<2>(W, Wt, K, N, tile);
}

// ---------------------------------------------------------------------------
// Kernel 3: MX-scaled fp8 GEMM (scales = 1.0), 256x256 tile, BK=128,
// 8 waves (2M x 4N), 4 phases per K-tile, counted-vmcnt rolling DMA (= r5).
//
// ROUND-7 SINGLE-VARIABLE CHANGE: MFMA shape 16x16x128 -> 32x32x64
// (mfma_scale_f32_32x32x64_f8f6f4, m59: 4686 TF). Rounds 1-6 pinned
// MfmaUtil at 19-24.5% across occupancy/blocks/phase-structure variations;
// the instruction is the last unvaried component. 32x32x64 halves the
// instruction count (16/wave/tile vs 32) and doubles FLOP/instr; every
// measured fast kernel on this chip (AITER fmha, m119) favors 32x32.
//
// Fragment addressing (same contiguous-32B-per-lane family as the verified
// 16x16x128): lane l holds row (l&31), k-bytes (l>>5)*32+0..31.
// In our unchanged LDS unit layout (unit u=(row>>4)*2+((kb>>4)&1),
// slot l'=(row&15)+((kb>>5)<<4), byte=u*1024+l'*16+(kb&15)) this is:
//   labase = ((l>>4)&1)*2048 + (l&15)*16 + (l>>5)*256
//   A frag(mb,ks): two b128 at (wm*8+mb*2)*2048 + ks*512 + labase (+1024)
//   B frag(nb,ks): two b128 at (wn*4+nb*2)*2048 + ks*512 + labase (+1024)
// Wave footprint: 4 dense 256 B chunks -> conflict-free by construction.
//
// Phases (per wave): P0: B ks0 + A mb0,1 ks0 (8 rd) | DMA A(t+1)[0,1]
//                    P1: B ks1 + A mb2,3 ks0 (8 rd) | DMA A(t+1)[2,3]
//                    P2: A mb0,1 ks1 (4 rd)         | DMA B(t+2)[0,1]
//                    P3: A mb2,3 ks1 (4 rd)         | DMA B(t+2)[2,3]
// Each phase: 4 fully independent MFMAs. B-reads confined to P0/P1 so the
// B(t+2) DMA (same buffer index as B(t)) is barrier-separated from all B(t)
// reads (every wave's lgkmcnt(0) precedes its P1-close barrier arrival;
// DMA issued only after P1-close). vmcnt(4) boundary keeps B(t+2)'s 4 loads
// in flight (FIFO walk verified for NT in {1,2,16}).
//
// Epilogue: per (mb,reg) row, both nb stores adjacent -> 256 B contiguous
// (fixes r5's 325 vs 256 MB write amplification).
// ---------------------------------------------------------------------------
__global__ __launch_bounds__(512, 2) void gemm_mxfp8_kernel(
    const unsigned char* __restrict__ A,   // [M,K] fp8
    const unsigned char* __restrict__ Bt,  // [N,K] fp8
    float* __restrict__ C,                 // [M,N] fp32
    const float* __restrict__ bias,        // [N]
    const float* __restrict__ wscale,
    const float* __restrict__ iscale,
    int M, int N, int K) {
    __shared__ __align__(16) unsigned char As[2 * 32768];
    __shared__ __align__(16) unsigned char Bs[2 * 32768];

    const int tid  = threadIdx.x;
    const int lane = tid & 63;
    const int wv   = tid >> 6;          // 8 waves
    const int wm   = wv >> 2;           // 2 (M) x 4 (N) wave grid
    const int wn   = wv & 3;
    const int r16  = lane & 15;
    const int cq   = lane >> 4;         // 0..3

    const int bm = blockIdx.y * 256;    // linear block order (round-2 measured)
    const int bn = blockIdx.x * 256;

    // staging: 32 x 1 KB units per operand tile; wave wv owns units wv*4+j
    // (UNCHANGED from rounds 1-6; verified conflict-free, correct)
    const unsigned char* ga[4];
    const unsigned char* gb[4];
    int lo[4];
#pragma unroll
    for (int j = 0; j < 4; ++j) {
        const int u   = wv * 4 + j;     // 0..31
        const int rb  = u >> 1;
        const int rg  = u & 1;
        const int row = rb * 16 + r16;
        const int col = cq * 32 + rg * 16;   // per-lane pre-swizzled source
        ga[j] = A  + (size_t)(bm + row) * K + col;
        gb[j] = Bt + (size_t)(bn + row) * K + col;
        lo[j] = u * 1024;                    // wave-uniform LDS offset
    }

    floatx16 acc[4][2] = {};            // 4 m-blocks x 2 n-blocks, 128 VGPR
    const int NT = K >> 7;              // K / 128

    // per-lane fragment base within a 2 KB unit-pair (derivation in header)
    const int labase = ((lane >> 4) & 1) * 2048 + (lane & 15) * 16 + (lane >> 5) * 256;

    // prologue: A(0)+B(0) -> buf0, B(1) -> buf1, wait all but newest 4
#pragma unroll
    for (int j = 0; j < 4; ++j) {
        gload16(ga[j], &As[lo[j]]);
        gload16(gb[j], &Bs[lo[j]]);
        ga[j] += 128; gb[j] += 128;
    }
    if (NT > 1) {
#pragma unroll
        for (int j = 0; j < 4; ++j) {
            gload16(gb[j], &Bs[32768 + lo[j]]);   // B(1) -> buf1
            gb[j] += 128;                         // gb now points at tile 2
        }
        asm volatile("s_waitcnt vmcnt(4)" ::: "memory");
    } else {
        asm volatile("s_waitcnt vmcnt(0)" ::: "memory");
    }
    __builtin_amdgcn_s_barrier();
    __builtin_amdgcn_sched_barrier(0);

    union U8 { intx8 v; uint4 q[2]; };

#define READ_FRAG(dst, p)                                           \
    do {                                                            \
        U8 _u;                                                      \
        _u.q[0] = *(const uint4*)(p);                               \
        _u.q[1] = *(const uint4*)((p) + 1024);                      \
        (dst) = _u.v;                                               \
    } while (0)

#define MFMA4(afA, afB, mA, mB, b0_, b1_)                                   \
    do {                                                                    \
        __builtin_amdgcn_s_setprio(1);                                      \
        acc[mA][0] = __builtin_amdgcn_mfma_scale_f32_32x32x64_f8f6f4(       \
            afA, b0_, acc[mA][0], 0, 0, 0, 0x7F7F7F7F, 0, 0x7F7F7F7F);      \
        acc[mA][1] = __builtin_amdgcn_mfma_scale_f32_32x32x64_f8f6f4(       \
            afA, b1_, acc[mA][1], 0, 0, 0, 0x7F7F7F7F, 0, 0x7F7F7F7F);      \
        acc[mB][0] = __builtin_amdgcn_mfma_scale_f32_32x32x64_f8f6f4(       \
            afB, b0_, acc[mB][0], 0, 0, 0, 0x7F7F7F7F, 0, 0x7F7F7F7F);      \
        acc[mB][1] = __builtin_amdgcn_mfma_scale_f32_32x32x64_f8f6f4(       \
            afB, b1_, acc[mB][1], 0, 0, 0, 0x7F7F7F7F, 0, 0x7F7F7F7F);      \
        __builtin_amdgcn_s_setprio(0);                                      \
    } while (0)

#define PHASE_WAIT()                                             \
    do {                                                         \
        __builtin_amdgcn_s_barrier();                            \
        asm volatile("s_waitcnt lgkmcnt(0)" ::: "memory");       \
        __builtin_amdgcn_sched_barrier(0);                       \
    } while (0)

    for (int kt = 0; kt < NT; ++kt) {
        const unsigned char* Ab = &As[(kt & 1) * 32768];
        const unsigned char* Bb = &Bs[(kt & 1) * 32768];
        unsigned char* An  = &As[((kt + 1) & 1) * 32768];  // A(t+1) target
        unsigned char* Bn2 = &Bs[(kt & 1) * 32768];        // B(t+2) target
        const bool pfA = (kt + 1 < NT);
        const bool pfB = (kt + 2 < NT);

        const unsigned char* aB = Ab + labase;   // A frag base
        const unsigned char* bB = Bb + labase;   // B frag base
        intx8 b00, b01, b10, b11, af0, af1;

        // ---- P0: B ks0 (nb0,nb1) + A ks0 (mb0,mb1); DMA A(t+1)[0,1]
        READ_FRAG(b00, bB + (wn * 4 + 0) * 2048);
        READ_FRAG(b01, bB + (wn * 4 + 2) * 2048);
        READ_FRAG(af0, aB + (wm * 8 + 0) * 2048);
        READ_FRAG(af1, aB + (wm * 8 + 2) * 2048);
        if (pfA) {
            gload16(ga[0], An + lo[0]); gload16(ga[1], An + lo[1]);
            ga[0] += 128; ga[1] += 128;
        }
        PHASE_WAIT();
        MFMA4(af0, af1, 0, 1, b00, b01);
        __builtin_amdgcn_s_barrier();

        // ---- P1: B ks1 (nb0,nb1) + A ks0 (mb2,mb3); DMA A(t+1)[2,3]
        READ_FRAG(b10, bB + (wn * 4 + 0) * 2048 + 512);
        READ_FRAG(b11, bB + (wn * 4 + 2) * 2048 + 512);
        READ_FRAG(af0, aB + (wm * 8 + 4) * 2048);
        READ_FRAG(af1, aB + (wm * 8 + 6) * 2048);
        if (pfA) {
            gload16(ga[2], An + lo[2]); gload16(ga[3], An + lo[3]);
            ga[2] += 128; ga[3] += 128;
        }
        PHASE_WAIT();
        MFMA4(af0, af1, 2, 3, b00, b01);
        __builtin_amdgcn_s_barrier();

        // ---- P2: A ks1 (mb0,mb1); DMA B(t+2)[0,1] (all B(t) reads done @P1)
        READ_FRAG(af0, aB + (wm * 8 + 0) * 2048 + 512);
        READ_FRAG(af1, aB + (wm * 8 + 2) * 2048 + 512);
        if (pfB) {
            gload16(gb[0], Bn2 + lo[0]); gload16(gb[1], Bn2 + lo[1]);
            gb[0] += 128; gb[1] += 128;
        }
        PHASE_WAIT();
        MFMA4(af0, af1, 0, 1, b10, b11);
        __builtin_amdgcn_s_barrier();

        // ---- P3: A ks1 (mb2,mb3); DMA B(t+2)[2,3]; counted boundary
        READ_FRAG(af0, aB + (wm * 8 + 4) * 2048 + 512);
        READ_FRAG(af1, aB + (wm * 8 + 6) * 2048 + 512);
        if (pfB) {
            gload16(gb[2], Bn2 + lo[2]); gload16(gb[3], Bn2 + lo[3]);
            gb[2] += 128; gb[3] += 128;
        }
        PHASE_WAIT();
        MFMA4(af0, af1, 2, 3, b10, b11);
        if (pfB) {      // steady state: keep newest 4 (B(t+2)) in flight
            asm volatile("s_waitcnt vmcnt(4)" ::: "memory");
        } else {        // tail: everything must land
            asm volatile("s_waitcnt vmcnt(0)" ::: "memory");
        }
        __builtin_amdgcn_s_barrier();
        __builtin_amdgcn_sched_barrier(0);
    }
    (void)M; (void)r16; (void)cq;
#undef READ_FRAG
#undef MFMA4
#undef PHASE_WAIT

    // epilogue: C/D 32x32 layout: col=lane&31, row=(r&3)+8*(r>>2)+4*(lane>>5)
    const float scale = iscale[0] * wscale[0];
    const int colb = bn + wn * 64 + (lane & 31);
    const float bv0 = bias[colb];
    const float bv1 = bias[colb + 32];
    const int rowb = bm + wm * 128 + 4 * (lane >> 5);
#pragma unroll
    for (int mb = 0; mb < 4; ++mb) {
#pragma unroll
        for (int r = 0; r < 16; ++r) {
            const int row = rowb + mb * 32 + (r & 3) + 8 * (r >> 2);
            float* cp = C + (size_t)row * N + colb;
            cp[0]  = acc[mb][0][r] * scale + bv0;   // 128 B across lanes
            cp[32] = acc[mb][1][r] * scale + bv1;   // adjacent 128 B
        }
    }
}

extern "C" void kernel_launch(void* const* d_in, const int* in_sizes, int n_in,
                              void* d_out, int out_size, void* d_ws, size_t ws_size,
                              hipStream_t stream) {
    const float* x          = (const float*)d_in[0];
    const unsigned char* w  = (const unsigned char*)d_in[1];
    const float* wscale     = (const float*)d_in[2];
    const float* iscale     = (const float*)d_in[3];
    const float* bias       = (const float*)d_in[4];
    float* out              = (float*)d_out;

    const int D_OUT = in_sizes[4];            // 8192
    const int D_IN  = in_sizes[1] / D_OUT;    // 2048
    const int M     = in_sizes[0] / D_IN;     // 8192

    int* flag         = (int*)d_ws;
    unsigned char* q  = (unsigned char*)d_ws + 256;
    unsigned char* wt = q + (size_t)M * D_IN;

    detect_kernel<<<1, 256, 0, stream>>>((const unsigned int*)w, flag);
    const int n8 = (M * D_IN) / 8;
    quant_kernel<<<(n8 + 255) / 256, 256, 0, stream>>>(x, (unsigned int*)q, iscale, n8);
    dim3 tg(D_OUT / 64, D_IN / 64);
    ingest_kernel<<<tg, 256, 0, stream>>>(w, wt, flag, D_IN, D_OUT);
    gemm_mxfp8_kernel<<<dim3(D_OUT / 256, M / 256), 512, 0, stream>>>(
        q, wt, out, bias, wscale, iscale, M, D_OUT, D_IN);
}